// Round 8
// baseline (52.472 us; speedup 1.0000x reference)
//
#include <hip/hip_runtime.h>

#define BB 4
#define DD 81
#define HH 256
#define WW 256
#define HW (HH*WW)
#define HW4 (HW/4)        // 16384 float4 per image plane
#define N4 (BB*HW4)       // 65536 float4-columns
#define NOUT4 (BB*DD*HW4) // 5308416 float4 outputs

__device__ __forceinline__ float4 f4min(float4 a, float4 b) {
    return float4{fminf(a.x, b.x), fminf(a.y, b.y), fminf(a.z, b.z), fminf(a.w, b.w)};
}

// ---------------------------------------------------------------------------
// Kernel 1: cmin = min over d of cost.
// 512-thread blocks: 64 float4-columns x 8 d-chunks (g=0 also covers plane 0).
// 1024 blocks -> 4 blocks/CU, up to 32 waves/CU; 10-deep fully-unrolled
// register batches keep ~10 loads in flight per thread. LDS combine.
// ---------------------------------------------------------------------------
__global__ __launch_bounds__(512, 4) void k_cmin(const float* __restrict__ cost,
                                                 float* __restrict__ cmin) {
    __shared__ float4 part[512];
    const int c    = threadIdx.x & 63;
    const int g    = threadIdx.x >> 6;          // [0,8)
    const int col4 = blockIdx.x * 64 + c;       // [0, N4)
    const int b    = col4 >> 14;
    const int hw4  = col4 & (HW4 - 1);
    const float4* s = reinterpret_cast<const float4*>(cost) + (size_t)b * DD * HW4 + hw4;

    const int d0 = 10 * g + 1;                  // g covers [d0, d0+10); g=0 also d=0
    const float4* p = s + (size_t)d0 * HW4;
    float4 v[10];
    #pragma unroll
    for (int j = 0; j < 10; ++j) v[j] = p[(size_t)j * HW4];
    float4 m = v[0];
    #pragma unroll
    for (int j = 1; j < 10; ++j) m = f4min(m, v[j]);
    if (g == 0) m = f4min(m, s[0]);             // plane 0

    part[threadIdx.x] = m;
    __syncthreads();
    if (g == 0) {
        float4 r = part[c];
        #pragma unroll
        for (int k = 1; k < 8; ++k) r = f4min(r, part[k * 64 + c]);
        reinterpret_cast<float4*>(cmin)[col4] = r;
    }
}

// ---------------------------------------------------------------------------
// Wave-parallel bidirectional linear-recurrence scan over 256 elements.
// m_j = c_j + e_j*m_{j-1}; operator (a,b) composes as cur∘prev =
// (a_c*a_p, a_c*b_p + b_c). g_j = e_j*m_{j-1} accumulated for both dirs.
// (validated rounds 2-7)
// ---------------------------------------------------------------------------
__device__ __forceinline__ void wave_scan_bidir(
        int lane, const float c[4], const float ef[4], const float eb[4], float g[4]) {
    float A = 1.f, B = 0.f;
    #pragma unroll
    for (int j = 0; j < 4; ++j) { B = ef[j] * B + c[j]; A = ef[j] * A; }
    #pragma unroll
    for (int d = 1; d < 64; d <<= 1) {
        float Ap = __shfl_up(A, d);
        float Bp = __shfl_up(B, d);
        if (lane >= d) { B = A * Bp + B; A = A * Ap; }
    }
    float m_in = __shfl_up(B, 1);
    if (lane == 0) m_in = 0.f;
    float m = m_in;
    #pragma unroll
    for (int j = 0; j < 4; ++j) { float t = ef[j] * m; g[j] = t; m = c[j] + t; }

    A = 1.f; B = 0.f;
    #pragma unroll
    for (int j = 3; j >= 0; --j) { B = eb[j] * B + c[j]; A = eb[j] * A; }
    #pragma unroll
    for (int d = 1; d < 64; d <<= 1) {
        float An = __shfl_down(A, d);
        float Bn = __shfl_down(B, d);
        if (lane + d < 64) { B = A * Bn + B; A = A * An; }
    }
    m_in = __shfl_down(B, 1);
    if (lane == 63) m_in = 0.f;
    m = m_in;
    #pragma unroll
    for (int j = 3; j >= 0; --j) { float t = eb[j] * m; g[j] += t; m = c[j] + t; }
}

// ---------------------------------------------------------------------------
// Kernel 2: waves [0,1024): horizontal rows (ch 0 fwd, ch 1 bwd) -> gh
//           waves [1024,2048): vertical cols (ch 2 down, ch 3 up) -> gv
// ---------------------------------------------------------------------------
__global__ void k_scan(const float* __restrict__ cmin, const float* __restrict__ edge,
                       float* __restrict__ gh, float* __restrict__ gv) {
    int tid  = blockIdx.x * blockDim.x + threadIdx.x;
    int wave = tid >> 6;
    int lane = tid & 63;
    float c[4], ef[4], eb[4], g[4];
    if (wave < BB * HH) {
        int b = wave >> 8, h = wave & (HH - 1);
        size_t row = (size_t)b * HW + (size_t)h * WW;
        float4 c4  = reinterpret_cast<const float4*>(cmin + row)[lane];
        float4 f4  = reinterpret_cast<const float4*>(edge + ((size_t)b * 4 + 0) * HW + (size_t)h * WW)[lane];
        float4 b4  = reinterpret_cast<const float4*>(edge + ((size_t)b * 4 + 1) * HW + (size_t)h * WW)[lane];
        c[0]=c4.x; c[1]=c4.y; c[2]=c4.z; c[3]=c4.w;
        ef[0]=f4.x; ef[1]=f4.y; ef[2]=f4.z; ef[3]=f4.w;
        eb[0]=b4.x; eb[1]=b4.y; eb[2]=b4.z; eb[3]=b4.w;
        wave_scan_bidir(lane, c, ef, eb, g);
        float4 o = {g[0], g[1], g[2], g[3]};
        reinterpret_cast<float4*>(gh + row)[lane] = o;
    } else if (wave < 2 * BB * HH) {
        int wv = wave - BB * HH;
        int b = wv >> 8, w = wv & (WW - 1);
        const float* cm = cmin + (size_t)b * HW + w;
        const float* e2 = edge + ((size_t)b * 4 + 2) * HW + w;
        const float* e3 = edge + ((size_t)b * 4 + 3) * HW + w;
        int r0 = lane * 4;
        #pragma unroll
        for (int j = 0; j < 4; ++j) {
            size_t off = (size_t)(r0 + j) * WW;
            c[j]  = cm[off];
            ef[j] = e2[off];
            eb[j] = e3[off];
        }
        wave_scan_bidir(lane, c, ef, eb, g);
        float* go = gv + (size_t)b * HW + w;
        #pragma unroll
        for (int j = 0; j < 4; ++j) go[(size_t)(r0 + j) * WW] = g[j];
    }
}

// ---------------------------------------------------------------------------
// Kernel 3: out = 4*cost + (gh+gv).  4 float4 per thread, grid-stride split
// (stride = total threads so each instruction stays wave-contiguous);
// all 12 loads issued before any compute/store -> 4x MLP per thread.
// NOUT4 = 4*T exactly, T = 1327104 = 5184 blocks * 256.
// ---------------------------------------------------------------------------
__global__ __launch_bounds__(256) void k_out(
        const float* __restrict__ cost, const float* __restrict__ gh,
        const float* __restrict__ gv, float* __restrict__ out) {
    const int T = NOUT4 / 4;
    int i = blockIdx.x * 256 + threadIdx.x;     // [0, T)
    const float4* c4 = reinterpret_cast<const float4*>(cost);
    const float4* a4 = reinterpret_cast<const float4*>(gh);
    const float4* v4 = reinterpret_cast<const float4*>(gv);
    float4*       o4 = reinterpret_cast<float4*>(out);

    int   e[4];
    float4 c[4], a[4], v[4];
    #pragma unroll
    for (int k = 0; k < 4; ++k) {
        e[k] = i + k * T;
        c[k] = c4[e[k]];
        int b   = e[k] / (DD * HW4);
        int gi  = (b << 14) + (e[k] & (HW4 - 1));   // b*HW4 + hw4
        a[k] = a4[gi];
        v[k] = v4[gi];
    }
    #pragma unroll
    for (int k = 0; k < 4; ++k) {
        float4 r;
        r.x = fmaf(c[k].x, 4.f, a[k].x + v[k].x);
        r.y = fmaf(c[k].y, 4.f, a[k].y + v[k].y);
        r.z = fmaf(c[k].z, 4.f, a[k].z + v[k].z);
        r.w = fmaf(c[k].w, 4.f, a[k].w + v[k].w);
        o4[e[k]] = r;
    }
}

extern "C" void kernel_launch(void* const* d_in, const int* in_sizes, int n_in,
                              void* d_out, int out_size, void* d_ws, size_t ws_size,
                              hipStream_t stream) {
    const float* cost = (const float*)d_in[0];
    const float* edge = (const float*)d_in[1];
    float* out = (float*)d_out;

    // ws layout: gh [1MB] | gv [1MB] | cmin [1MB]
    float* gh   = (float*)d_ws;
    float* gv   = gh + (size_t)BB * HW;
    float* cmin = gv + (size_t)BB * HW;

    {   // 1: cmin, 1024 blocks x 512
        k_cmin<<<dim3(N4 / 64), dim3(512), 0, stream>>>(cost, cmin);
    }
    {   // 2: scans, 2048 waves = 131072 threads
        int n = 2 * BB * HH * 64;
        k_scan<<<dim3((n + 255) / 256), dim3(256), 0, stream>>>(cmin, edge, gh, gv);
    }
    {   // 3: output, 5184 blocks x 256, 4 float4/thread
        k_out<<<dim3(NOUT4 / 4 / 256), dim3(256), 0, stream>>>(cost, gh, gv, out);
    }
}

// Round 9
// 51.996 us; speedup vs baseline: 1.0091x; 1.0091x over previous
//
#include <hip/hip_runtime.h>

#define BB 4
#define DD 81
#define HH 256
#define WW 256
#define HW (HH*WW)
#define HW4 (HW/4)        // 16384 float4 per image plane
#define N4 (BB*HW4)       // 65536 float4-columns
#define NOUT4 (BB*DD*HW4) // 5308416 float4 outputs

typedef float v4f __attribute__((ext_vector_type(4)));

__device__ __forceinline__ float4 f4min(float4 a, float4 b) {
    return float4{fminf(a.x, b.x), fminf(a.y, b.y), fminf(a.z, b.z), fminf(a.w, b.w)};
}

// ---------------------------------------------------------------------------
// Kernel 1: cmin = min over d of cost. (structure validated R8)
// 512-thread blocks: 64 float4-columns x 8 d-chunks; 10-deep register batches.
// With NT out-stores (k_out), cost stays L3-resident across graph replays ->
// this kernel should run at L3 read BW, not HBM.
// ---------------------------------------------------------------------------
__global__ __launch_bounds__(512, 4) void k_cmin(const float* __restrict__ cost,
                                                 float* __restrict__ cmin) {
    __shared__ float4 part[512];
    const int c    = threadIdx.x & 63;
    const int g    = threadIdx.x >> 6;          // [0,8)
    const int col4 = blockIdx.x * 64 + c;       // [0, N4)
    const int b    = col4 >> 14;
    const int hw4  = col4 & (HW4 - 1);
    const float4* s = reinterpret_cast<const float4*>(cost) + (size_t)b * DD * HW4 + hw4;

    const int d0 = 10 * g + 1;                  // g covers [d0, d0+10); g=0 also d=0
    const float4* p = s + (size_t)d0 * HW4;
    float4 v[10];
    #pragma unroll
    for (int j = 0; j < 10; ++j) v[j] = p[(size_t)j * HW4];
    float4 m = v[0];
    #pragma unroll
    for (int j = 1; j < 10; ++j) m = f4min(m, v[j]);
    if (g == 0) m = f4min(m, s[0]);             // plane 0

    part[threadIdx.x] = m;
    __syncthreads();
    if (g == 0) {
        float4 r = part[c];
        #pragma unroll
        for (int k = 1; k < 8; ++k) r = f4min(r, part[k * 64 + c]);
        reinterpret_cast<float4*>(cmin)[col4] = r;
    }
}

// ---------------------------------------------------------------------------
// Wave-parallel bidirectional linear-recurrence scan over 256 elements.
// m_j = c_j + e_j*m_{j-1}; operator (a,b) composes as cur∘prev =
// (a_c*a_p, a_c*b_p + b_c). g_j = e_j*m_{j-1} accumulated for both dirs.
// (validated rounds 2-8)
// ---------------------------------------------------------------------------
__device__ __forceinline__ void wave_scan_bidir(
        int lane, const float c[4], const float ef[4], const float eb[4], float g[4]) {
    float A = 1.f, B = 0.f;
    #pragma unroll
    for (int j = 0; j < 4; ++j) { B = ef[j] * B + c[j]; A = ef[j] * A; }
    #pragma unroll
    for (int d = 1; d < 64; d <<= 1) {
        float Ap = __shfl_up(A, d);
        float Bp = __shfl_up(B, d);
        if (lane >= d) { B = A * Bp + B; A = A * Ap; }
    }
    float m_in = __shfl_up(B, 1);
    if (lane == 0) m_in = 0.f;
    float m = m_in;
    #pragma unroll
    for (int j = 0; j < 4; ++j) { float t = ef[j] * m; g[j] = t; m = c[j] + t; }

    A = 1.f; B = 0.f;
    #pragma unroll
    for (int j = 3; j >= 0; --j) { B = eb[j] * B + c[j]; A = eb[j] * A; }
    #pragma unroll
    for (int d = 1; d < 64; d <<= 1) {
        float An = __shfl_down(A, d);
        float Bn = __shfl_down(B, d);
        if (lane + d < 64) { B = A * Bn + B; A = A * An; }
    }
    m_in = __shfl_down(B, 1);
    if (lane == 63) m_in = 0.f;
    m = m_in;
    #pragma unroll
    for (int j = 3; j >= 0; --j) { float t = eb[j] * m; g[j] += t; m = c[j] + t; }
}

// ---------------------------------------------------------------------------
// Kernel 2: waves [0,1024): horizontal rows (ch 0 fwd, ch 1 bwd) -> gh
//           waves [1024,2048): vertical cols (ch 2 down, ch 3 up) -> gv
// ---------------------------------------------------------------------------
__global__ void k_scan(const float* __restrict__ cmin, const float* __restrict__ edge,
                       float* __restrict__ gh, float* __restrict__ gv) {
    int tid  = blockIdx.x * blockDim.x + threadIdx.x;
    int wave = tid >> 6;
    int lane = tid & 63;
    float c[4], ef[4], eb[4], g[4];
    if (wave < BB * HH) {
        int b = wave >> 8, h = wave & (HH - 1);
        size_t row = (size_t)b * HW + (size_t)h * WW;
        float4 c4  = reinterpret_cast<const float4*>(cmin + row)[lane];
        float4 f4  = reinterpret_cast<const float4*>(edge + ((size_t)b * 4 + 0) * HW + (size_t)h * WW)[lane];
        float4 b4  = reinterpret_cast<const float4*>(edge + ((size_t)b * 4 + 1) * HW + (size_t)h * WW)[lane];
        c[0]=c4.x; c[1]=c4.y; c[2]=c4.z; c[3]=c4.w;
        ef[0]=f4.x; ef[1]=f4.y; ef[2]=f4.z; ef[3]=f4.w;
        eb[0]=b4.x; eb[1]=b4.y; eb[2]=b4.z; eb[3]=b4.w;
        wave_scan_bidir(lane, c, ef, eb, g);
        float4 o = {g[0], g[1], g[2], g[3]};
        reinterpret_cast<float4*>(gh + row)[lane] = o;
    } else if (wave < 2 * BB * HH) {
        int wv = wave - BB * HH;
        int b = wv >> 8, w = wv & (WW - 1);
        const float* cm = cmin + (size_t)b * HW + w;
        const float* e2 = edge + ((size_t)b * 4 + 2) * HW + w;
        const float* e3 = edge + ((size_t)b * 4 + 3) * HW + w;
        int r0 = lane * 4;
        #pragma unroll
        for (int j = 0; j < 4; ++j) {
            size_t off = (size_t)(r0 + j) * WW;
            c[j]  = cm[off];
            ef[j] = e2[off];
            eb[j] = e3[off];
        }
        wave_scan_bidir(lane, c, ef, eb, g);
        float* go = gv + (size_t)b * HW + w;
        #pragma unroll
        for (int j = 0; j < 4; ++j) go[(size_t)(r0 + j) * WW] = g[j];
    }
}

// ---------------------------------------------------------------------------
// Kernel 3: out = 4*cost + (gh+gv).  4 float4/thread (one per batch b=k).
// NON-TEMPORAL stores: out is write-once-never-read; the nt hint keeps it
// from evicting cost (85 MB) out of the 256 MB L3, so the next iteration's
// k_cmin reads cost from L3 instead of HBM.
// ---------------------------------------------------------------------------
__global__ __launch_bounds__(256) void k_out(
        const float* __restrict__ cost, const float* __restrict__ gh,
        const float* __restrict__ gv, float* __restrict__ out) {
    const int T = NOUT4 / 4;                    // = DD*HW4 (one batch's float4s)
    int i = blockIdx.x * 256 + threadIdx.x;     // [0, T)
    const float4* c4 = reinterpret_cast<const float4*>(cost);
    const float4* a4 = reinterpret_cast<const float4*>(gh);
    const float4* v4 = reinterpret_cast<const float4*>(gv);
    v4f*          o4 = reinterpret_cast<v4f*>(out);

    int   e[4];
    float4 c[4], a[4], v[4];
    #pragma unroll
    for (int k = 0; k < 4; ++k) {
        e[k] = i + k * T;                       // batch k, same (d,hw)
        c[k] = c4[e[k]];
        int gi = (k << 14) + (e[k] & (HW4 - 1));    // k*HW4 + hw4
        a[k] = a4[gi];
        v[k] = v4[gi];
    }
    #pragma unroll
    for (int k = 0; k < 4; ++k) {
        v4f r;
        r.x = fmaf(c[k].x, 4.f, a[k].x + v[k].x);
        r.y = fmaf(c[k].y, 4.f, a[k].y + v[k].y);
        r.z = fmaf(c[k].z, 4.f, a[k].z + v[k].z);
        r.w = fmaf(c[k].w, 4.f, a[k].w + v[k].w);
        __builtin_nontemporal_store(r, &o4[e[k]]);
    }
}

extern "C" void kernel_launch(void* const* d_in, const int* in_sizes, int n_in,
                              void* d_out, int out_size, void* d_ws, size_t ws_size,
                              hipStream_t stream) {
    const float* cost = (const float*)d_in[0];
    const float* edge = (const float*)d_in[1];
    float* out = (float*)d_out;

    // ws layout: gh [1MB] | gv [1MB] | cmin [1MB]
    float* gh   = (float*)d_ws;
    float* gv   = gh + (size_t)BB * HW;
    float* cmin = gv + (size_t)BB * HW;

    {   // 1: cmin, 1024 blocks x 512
        k_cmin<<<dim3(N4 / 64), dim3(512), 0, stream>>>(cost, cmin);
    }
    {   // 2: scans, 2048 waves = 131072 threads
        int n = 2 * BB * HH * 64;
        k_scan<<<dim3((n + 255) / 256), dim3(256), 0, stream>>>(cmin, edge, gh, gv);
    }
    {   // 3: output, 5184 blocks x 256, 4 float4/thread, NT stores
        k_out<<<dim3(NOUT4 / 4 / 256), dim3(256), 0, stream>>>(cost, gh, gv, out);
    }
}